// Round 2
// baseline (292.114 us; speedup 1.0000x reference)
//
#include <hip/hip_runtime.h>
#include <math.h>

#define D_MODEL   2048
#define N_EXPERTS 64
#define TOP_K     8
#define N_TOKENS  16384

#define TOK_TILE  64
#define KC        128
#define NCHUNK    (D_MODEL / KC)   // 16
#define NTHREADS  512
#define EXP_PER_WAVE 8             // 64 experts / 8 waves

__global__ __launch_bounds__(NTHREADS) void router_kernel(
    const float* __restrict__ x, const float* __restrict__ gw,
    float* __restrict__ out)
{
    // stride 132 floats: start bank = 4*lane mod 32 for per-row b128 reads
    // (same multiset as contiguous b128 = conflict-free minimum)
    __shared__ __align__(16) float xs[2][TOK_TILE][KC + 4];
    __shared__ float lt[TOK_TILE][N_EXPERTS + 1];
    __shared__ float smax[TOK_TILE], srs[TOK_TILE];

    const int tid  = threadIdx.x;
    const int lane = tid & 63;          // token within tile
    const int wv   = tid >> 6;          // wave id 0..7
    const int m0   = blockIdx.x * TOK_TILE;

    // staging coords: 64 rows x 128 floats = 2048 float4; 512 thr x 4 float4
    const int r  = tid >> 3;            // 0..63
    const int cb = (tid & 7) * 4;       // 0,4,...,28 ; +32q covers 128 floats

    const float* xbase = x + (size_t)(m0 + r) * D_MODEL + cb;

    // prologue: chunk 0 -> regs -> buf0
    float4 xr0 = *(const float4*)(xbase);
    float4 xr1 = *(const float4*)(xbase + 32);
    float4 xr2 = *(const float4*)(xbase + 64);
    float4 xr3 = *(const float4*)(xbase + 96);
    *(float4*)&xs[0][r][cb +  0] = xr0;
    *(float4*)&xs[0][r][cb + 32] = xr1;
    *(float4*)&xs[0][r][cb + 64] = xr2;
    *(float4*)&xs[0][r][cb + 96] = xr3;
    __syncthreads();

    float acc[EXP_PER_WAVE];
#pragma unroll
    for (int i = 0; i < EXP_PER_WAVE; ++i) acc[i] = 0.f;

    // force wave-uniform expert base so w loads scalarize (s_load, not LDS/VMEM)
    const int e0u = __builtin_amdgcn_readfirstlane(wv) * EXP_PER_WAVE;
    const float* wbase = gw + (size_t)e0u * D_MODEL;

    for (int c = 0; c < NCHUNK; ++c) {
        // issue next chunk's global loads early; latency hides under compute
        if (c + 1 < NCHUNK) {
            const float* p = xbase + (c + 1) * KC;
            xr0 = *(const float4*)(p);
            xr1 = *(const float4*)(p + 32);
            xr2 = *(const float4*)(p + 64);
            xr3 = *(const float4*)(p + 96);
        }

        const int buf = c & 1;
#pragma unroll 8
        for (int k4 = 0; k4 < KC / 4; ++k4) {
            const float4 xv = *(const float4*)&xs[buf][lane][k4 * 4];
#pragma unroll
            for (int e = 0; e < EXP_PER_WAVE; ++e) {
                // fully uniform index -> scalar load from L2-resident gate_w
                const float4 w4 = *(const float4*)(wbase + (size_t)e * D_MODEL
                                                   + c * KC + k4 * 4);
                acc[e] = fmaf(xv.x, w4.x, acc[e]);
                acc[e] = fmaf(xv.y, w4.y, acc[e]);
                acc[e] = fmaf(xv.z, w4.z, acc[e]);
                acc[e] = fmaf(xv.w, w4.w, acc[e]);
            }
        }

        // write next chunk into the other buffer (WAR-safe: readers of this
        // buffer finished at the previous barrier)
        if (c + 1 < NCHUNK) {
            const int nb = (c + 1) & 1;
            *(float4*)&xs[nb][r][cb +  0] = xr0;
            *(float4*)&xs[nb][r][cb + 32] = xr1;
            *(float4*)&xs[nb][r][cb + 64] = xr2;
            *(float4*)&xs[nb][r][cb + 96] = xr3;
        }
        __syncthreads();
    }

    // scatter accumulators into logits tile
#pragma unroll
    for (int e = 0; e < EXP_PER_WAVE; ++e) lt[lane][e0u + e] = acc[e];
    __syncthreads();

    float* out_idx = out;
    float* out_w   = out + (size_t)N_TOKENS * TOP_K;
    float* out_p   = out + (size_t)2 * N_TOKENS * TOP_K;
    float* out_l   = out_p + (size_t)N_TOKENS * N_EXPERTS;

    if (tid < TOK_TILE) {
        const int t = tid;
        float tv[TOP_K];
        int   ti[TOP_K];
#pragma unroll
        for (int i = 0; i < TOP_K; ++i) { tv[i] = -INFINITY; ti[i] = 0; }
        float m = -INFINITY;

        for (int e = 0; e < N_EXPERTS; ++e) {
            const float v = lt[t][e];
            m = fmaxf(m, v);
            const bool beat_last = (v > tv[TOP_K - 1]);
            if (beat_last) {
#pragma unroll
                for (int j = TOP_K - 1; j >= 1; --j) {
                    const bool shift = (v > tv[j - 1]);
                    const bool here  = (v > tv[j]);
                    const float ntv = shift ? tv[j - 1] : (here ? v : tv[j]);
                    const int   nti = shift ? ti[j - 1] : (here ? e : ti[j]);
                    tv[j] = ntv; ti[j] = nti;
                }
                if (v > tv[0]) { tv[0] = v; ti[0] = e; }
            }
        }

        float s = 0.f;
        for (int e = 0; e < N_EXPERTS; ++e) s += expf(lt[t][e] - m);
        const float rs = 1.f / s;
        smax[t] = m;
        srs[t]  = rs;

        float ex[TOP_K];
        float wsum = 0.f;
#pragma unroll
        for (int i = 0; i < TOP_K; ++i) { ex[i] = expf(tv[i] - tv[0]); wsum += ex[i]; }
        const float rw = 1.f / wsum;

        const int tok = m0 + t;
#pragma unroll
        for (int i = 0; i < TOP_K; ++i) {
            out_idx[(size_t)tok * TOP_K + i] = (float)ti[i];
            out_w  [(size_t)tok * TOP_K + i] = ex[i] * rw;
        }
    }
    __syncthreads();

    // cooperative coalesced float4 writes of full_probs and logits
#pragma unroll
    for (int rep = 0; rep < 2; ++rep) {
        const int f = rep * (NTHREADS * 4) + tid * 4;   // 0..4092, step 4
        const int t = f >> 6;
        const int e = f & 63;
        const float l0 = lt[t][e + 0];
        const float l1 = lt[t][e + 1];
        const float l2 = lt[t][e + 2];
        const float l3 = lt[t][e + 3];
        const float mm = smax[t];
        const float rr = srs[t];
        float4 pv = make_float4(expf(l0 - mm) * rr, expf(l1 - mm) * rr,
                                expf(l2 - mm) * rr, expf(l3 - mm) * rr);
        float4 lv = make_float4(l0, l1, l2, l3);
        const size_t gbase = (size_t)m0 * N_EXPERTS + f;
        *(float4*)(out_p + gbase) = pv;
        *(float4*)(out_l + gbase) = lv;
    }
}

extern "C" void kernel_launch(void* const* d_in, const int* in_sizes, int n_in,
                              void* d_out, int out_size, void* d_ws, size_t ws_size,
                              hipStream_t stream) {
    const float* x  = (const float*)d_in[0];
    const float* gw = (const float*)d_in[1];
    float* out = (float*)d_out;
    router_kernel<<<dim3(N_TOKENS / TOK_TILE), dim3(NTHREADS), 0, stream>>>(x, gw, out);
}

// Round 3
// 74.786 us; speedup vs baseline: 3.9060x; 3.9060x over previous
//
#include <hip/hip_runtime.h>
#include <math.h>

#define D_MODEL   2048
#define N_EXPERTS 64
#define TOP_K     8
#define N_TOKENS  16384
#define TOK_TILE  64
#define NTHREADS  512
// ws layout: [kstep 0..63][nfrag 0..3][ver 0..2][lane 0..63][4 dwords]
#define WS_NEED   (64*4*3*64*16)   // 786432 bytes

typedef __attribute__((ext_vector_type(8))) short bf16x8;
typedef __attribute__((ext_vector_type(4))) float f32x4;
typedef __attribute__((ext_vector_type(4))) int   i32x4;

union FragU { i32x4 i; bf16x8 h; };

// exact 3-way truncation split: x == h+m+l + eps, |eps| <= 2^-24 |x|
__device__ __forceinline__ void split3(float x, unsigned &h, unsigned &m, unsigned &l) {
    unsigned ux = __float_as_uint(x);
    h = ux & 0xffff0000u;
    float mf = x - __uint_as_float(h);       // exact (Sterbenz)
    unsigned um = __float_as_uint(mf) & 0xffff0000u;
    float lf = mf - __uint_as_float(um);     // exact
    m = um;
    l = __float_as_uint(lf) & 0xffff0000u;
}

__global__ __launch_bounds__(256) void pack_w_kernel(const float* __restrict__ gw,
                                                     unsigned* __restrict__ wp) {
    const int g    = blockIdx.x * 256 + threadIdx.x;   // 0..196607
    const int d    = g & 3;
    const int lane = (g >> 2) & 63;
    const int rest = g >> 8;                           // 0..767
    const int v    = rest % 3;
    const int t    = rest / 3;                         // ks*4 + fr
    const int fr   = t & 3;
    const int ks   = t >> 2;
    const int e    = fr * 16 + (lane & 15);            // B col = lane&15
    const int k    = ks * 32 + (lane >> 4) * 8 + 2 * d;
    const float w0 = gw[(size_t)e * D_MODEL + k];
    const float w1 = gw[(size_t)e * D_MODEL + k + 1];
    unsigned h0, m0, l0, h1, m1, l1;
    split3(w0, h0, m0, l0);
    split3(w1, h1, m1, l1);
    const unsigned c0 = (v == 0) ? h0 : ((v == 1) ? m0 : l0);
    const unsigned c1 = (v == 0) ? h1 : ((v == 1) ? m1 : l1);
    wp[g] = (c0 >> 16) | c1;                           // low short = elem0
}

__device__ __forceinline__ void splitpack(const float4 a, const float4 b,
                                          FragU &ph, FragU &pm, FragU &pl) {
    const float f[8] = {a.x, a.y, a.z, a.w, b.x, b.y, b.z, b.w};
#pragma unroll
    for (int d = 0; d < 4; ++d) {
        unsigned h0, m0, l0, h1, m1, l1;
        split3(f[2 * d],     h0, m0, l0);
        split3(f[2 * d + 1], h1, m1, l1);
        ph.i[d] = (int)((h0 >> 16) | h1);
        pm.i[d] = (int)((m0 >> 16) | m1);
        pl.i[d] = (int)((l0 >> 16) | l1);
    }
}

#define MFMA(A_, B_, C_) C_ = __builtin_amdgcn_mfma_f32_16x16x32_bf16((A_).h, (B_).h, C_, 0, 0, 0)

__global__ __launch_bounds__(NTHREADS) void router_mfma(
    const float* __restrict__ x, const unsigned* __restrict__ wp,
    float* __restrict__ out)
{
    __shared__ float lt[TOK_TILE][N_EXPERTS + 1];
    __shared__ float smax[TOK_TILE], srs[TOK_TILE];

    const int tid  = threadIdx.x;
    const int lane = tid & 63;
    const int wv   = tid >> 6;          // 0..7
    const int mrow = wv & 1;            // token half (32)
    const int ncol = (wv >> 1) & 1;     // expert half (32)
    const int kh   = wv >> 2;           // K-split half
    const int m0   = blockIdx.x * TOK_TILE;

    const int lrow = lane & 15;         // A row / B col / C col
    const int lk   = lane >> 4;         // k-block 0..3

    const float* xr0 = x + (size_t)(m0 + mrow * 32 + lrow) * D_MODEL + lk * 8;
    const float* xr1 = xr0 + (size_t)16 * D_MODEL;

    f32x4 acc00 = {0.f, 0.f, 0.f, 0.f};
    f32x4 acc01 = acc00, acc10 = acc00, acc11 = acc00;

    const unsigned* wb = wp + (size_t)(ncol * 2 * 3) * 256 + lane * 4;

    // prologue: load kstep = kh
    int ks = kh;
    float4 A0a = *(const float4*)(xr0 + ks * 32);
    float4 A0b = *(const float4*)(xr0 + ks * 32 + 4);
    float4 A1a = *(const float4*)(xr1 + ks * 32);
    float4 A1b = *(const float4*)(xr1 + ks * 32 + 4);
    const unsigned* bt = wb + ks * 3072;
    i32x4 B0h = *(const i32x4*)(bt +    0);
    i32x4 B0m = *(const i32x4*)(bt +  256);
    i32x4 B0l = *(const i32x4*)(bt +  512);
    i32x4 B1h = *(const i32x4*)(bt +  768);
    i32x4 B1m = *(const i32x4*)(bt + 1024);
    i32x4 B1l = *(const i32x4*)(bt + 1280);

    auto compute = [&](float4 cA0a, float4 cA0b, float4 cA1a, float4 cA1b,
                       i32x4 cB0h, i32x4 cB0m, i32x4 cB0l,
                       i32x4 cB1h, i32x4 cB1m, i32x4 cB1l) {
        FragU a0h, a0m, a0l, a1h, a1m, a1l;
        splitpack(cA0a, cA0b, a0h, a0m, a0l);
        splitpack(cA1a, cA1b, a1h, a1m, a1l);
        FragU b0h, b0m, b0l, b1h, b1m, b1l;
        b0h.i = cB0h; b0m.i = cB0m; b0l.i = cB0l;
        b1h.i = cB1h; b1m.i = cB1m; b1l.i = cB1l;
        // 6-term split product per fragment pair: hh + hm + mh + hl + lh + mm
        MFMA(a0h, b0h, acc00); MFMA(a0h, b0m, acc00); MFMA(a0m, b0h, acc00);
        MFMA(a0h, b0l, acc00); MFMA(a0l, b0h, acc00); MFMA(a0m, b0m, acc00);
        MFMA(a0h, b1h, acc01); MFMA(a0h, b1m, acc01); MFMA(a0m, b1h, acc01);
        MFMA(a0h, b1l, acc01); MFMA(a0l, b1h, acc01); MFMA(a0m, b1m, acc01);
        MFMA(a1h, b0h, acc10); MFMA(a1h, b0m, acc10); MFMA(a1m, b0h, acc10);
        MFMA(a1h, b0l, acc10); MFMA(a1l, b0h, acc10); MFMA(a1m, b0m, acc10);
        MFMA(a1h, b1h, acc11); MFMA(a1h, b1m, acc11); MFMA(a1m, b1h, acc11);
        MFMA(a1h, b1l, acc11); MFMA(a1l, b1h, acc11); MFMA(a1m, b1m, acc11);
    };

    for (int t = 0; t < 31; ++t) {
        const int ks2 = ks + 2;
        // prefetch next kstep (no barriers anywhere -> loads fly under MFMAs)
        float4 N0a = *(const float4*)(xr0 + ks2 * 32);
        float4 N0b = *(const float4*)(xr0 + ks2 * 32 + 4);
        float4 N1a = *(const float4*)(xr1 + ks2 * 32);
        float4 N1b = *(const float4*)(xr1 + ks2 * 32 + 4);
        const unsigned* bt2 = wb + ks2 * 3072;
        i32x4 C0h = *(const i32x4*)(bt2 +    0);
        i32x4 C0m = *(const i32x4*)(bt2 +  256);
        i32x4 C0l = *(const i32x4*)(bt2 +  512);
        i32x4 C1h = *(const i32x4*)(bt2 +  768);
        i32x4 C1m = *(const i32x4*)(bt2 + 1024);
        i32x4 C1l = *(const i32x4*)(bt2 + 1280);

        compute(A0a, A0b, A1a, A1b, B0h, B0m, B0l, B1h, B1m, B1l);

        A0a = N0a; A0b = N0b; A1a = N1a; A1b = N1b;
        B0h = C0h; B0m = C0m; B0l = C0l; B1h = C1h; B1m = C1m; B1l = C1l;
        ks = ks2;
    }
    compute(A0a, A0b, A1a, A1b, B0h, B0m, B0l, B1h, B1m, B1l);

    // ---- reduce the two K-halves into lt ----
    // C layout (m89-verified): col = lane&15, row = (lane>>4)*4 + reg
    if (kh == 1) {
#pragma unroll
        for (int r = 0; r < 4; ++r) {
            lt[mrow * 32 +  0 + lk * 4 + r][ncol * 32 +  0 + lrow] = acc00[r];
            lt[mrow * 32 +  0 + lk * 4 + r][ncol * 32 + 16 + lrow] = acc01[r];
            lt[mrow * 32 + 16 + lk * 4 + r][ncol * 32 +  0 + lrow] = acc10[r];
            lt[mrow * 32 + 16 + lk * 4 + r][ncol * 32 + 16 + lrow] = acc11[r];
        }
    }
    __syncthreads();
    if (kh == 0) {
#pragma unroll
        for (int r = 0; r < 4; ++r) {
            lt[mrow * 32 +  0 + lk * 4 + r][ncol * 32 +  0 + lrow] += acc00[r];
            lt[mrow * 32 +  0 + lk * 4 + r][ncol * 32 + 16 + lrow] += acc01[r];
            lt[mrow * 32 + 16 + lk * 4 + r][ncol * 32 +  0 + lrow] += acc10[r];
            lt[mrow * 32 + 16 + lk * 4 + r][ncol * 32 + 16 + lrow] += acc11[r];
        }
    }
    __syncthreads();

    // ---- epilogue: identical to the R0-proven path ----
    float* out_idx = out;
    float* out_w   = out + (size_t)N_TOKENS * TOP_K;
    float* out_p   = out + (size_t)2 * N_TOKENS * TOP_K;
    float* out_l   = out_p + (size_t)N_TOKENS * N_EXPERTS;

    if (tid < TOK_TILE) {
        const int t = tid;
        float tv[TOP_K];
        int   ti[TOP_K];
#pragma unroll
        for (int i = 0; i < TOP_K; ++i) { tv[i] = -INFINITY; ti[i] = 0; }
        float m = -INFINITY;

        for (int e = 0; e < N_EXPERTS; ++e) {
            const float v = lt[t][e];
            m = fmaxf(m, v);
            if (v > tv[TOP_K - 1]) {
#pragma unroll
                for (int j = TOP_K - 1; j >= 1; --j) {
                    const bool shift = (v > tv[j - 1]);
                    const bool here  = (v > tv[j]);
                    const float ntv = shift ? tv[j - 1] : (here ? v : tv[j]);
                    const int   nti = shift ? ti[j - 1] : (here ? e : ti[j]);
                    tv[j] = ntv; ti[j] = nti;
                }
                if (v > tv[0]) { tv[0] = v; ti[0] = e; }
            }
        }

        float s = 0.f;
        for (int e = 0; e < N_EXPERTS; ++e) s += expf(lt[t][e] - m);
        const float rs = 1.f / s;
        smax[t] = m;
        srs[t]  = rs;

        float ex[TOP_K];
        float wsum = 0.f;
#pragma unroll
        for (int i = 0; i < TOP_K; ++i) { ex[i] = expf(tv[i] - tv[0]); wsum += ex[i]; }
        const float rw = 1.f / wsum;

        const int tok = m0 + t;
#pragma unroll
        for (int i = 0; i < TOP_K; ++i) {
            out_idx[(size_t)tok * TOP_K + i] = (float)ti[i];
            out_w  [(size_t)tok * TOP_K + i] = ex[i] * rw;
        }
    }
    __syncthreads();

#pragma unroll
    for (int rep = 0; rep < 2; ++rep) {
        const int f = rep * (NTHREADS * 4) + tid * 4;
        const int t = f >> 6;
        const int e = f & 63;
        const float l0 = lt[t][e + 0];
        const float l1 = lt[t][e + 1];
        const float l2 = lt[t][e + 2];
        const float l3 = lt[t][e + 3];
        const float mm = smax[t];
        const float rr = srs[t];
        float4 pv = make_float4(expf(l0 - mm) * rr, expf(l1 - mm) * rr,
                                expf(l2 - mm) * rr, expf(l3 - mm) * rr);
        float4 lv = make_float4(l0, l1, l2, l3);
        const size_t gbase = (size_t)m0 * N_EXPERTS + f;
        *(float4*)(out_p + gbase) = pv;
        *(float4*)(out_l + gbase) = lv;
    }
}

// ---------------- fallback (R0-proven fp32 path) if ws too small ----------------
__global__ __launch_bounds__(NTHREADS) void router_fallback(
    const float* __restrict__ x, const float* __restrict__ gw,
    float* __restrict__ out)
{
    __shared__ float xs[TOK_TILE][33];
    __shared__ float wsh[N_EXPERTS][36];
    __shared__ float lt[TOK_TILE][N_EXPERTS + 1];
    __shared__ float smax[TOK_TILE], srs[TOK_TILE];

    const int tid  = threadIdx.x;
    const int lane = tid & 63;
    const int wv   = tid >> 6;
    const int m0   = blockIdx.x * TOK_TILE;
    const int srow = tid >> 3;
    const int skq  = (tid & 7) * 4;

    const float* xsrc = x  + (size_t)(m0 + srow) * D_MODEL + skq;
    const float* wsrc = gw + (size_t)srow        * D_MODEL + skq;
    float4 xr = *(const float4*)(xsrc);
    float4 wr = *(const float4*)(wsrc);

    float acc[8];
#pragma unroll
    for (int i = 0; i < 8; ++i) acc[i] = 0.f;
    const int e0 = wv * 8;

    for (int c = 0; c < D_MODEL / 32; ++c) {
        xs[srow][skq] = xr.x; xs[srow][skq+1] = xr.y; xs[srow][skq+2] = xr.z; xs[srow][skq+3] = xr.w;
        *(float4*)&wsh[srow][skq] = wr;
        __syncthreads();
        if (c + 1 < D_MODEL / 32) {
            xr = *(const float4*)(xsrc + (c + 1) * 32);
            wr = *(const float4*)(wsrc + (c + 1) * 32);
        }
#pragma unroll 8
        for (int k4 = 0; k4 < 8; ++k4) {
            const float4 xv = *(const float4*)&xs[lane][k4 * 4];
#pragma unroll
            for (int e = 0; e < 8; ++e) {
                const float4 w4 = *(const float4*)&wsh[e0 + e][k4 * 4];
                acc[e] = fmaf(xv.x, w4.x, fmaf(xv.y, w4.y, fmaf(xv.z, w4.z, fmaf(xv.w, w4.w, acc[e]))));
            }
        }
        __syncthreads();
    }
#pragma unroll
    for (int e = 0; e < 8; ++e) lt[lane][e0 + e] = acc[e];
    __syncthreads();

    float* out_idx = out;
    float* out_w   = out + (size_t)N_TOKENS * TOP_K;
    float* out_p   = out + (size_t)2 * N_TOKENS * TOP_K;
    float* out_l   = out_p + (size_t)N_TOKENS * N_EXPERTS;

    if (tid < TOK_TILE) {
        const int t = tid;
        float tv[TOP_K]; int ti[TOP_K];
#pragma unroll
        for (int i = 0; i < TOP_K; ++i) { tv[i] = -INFINITY; ti[i] = 0; }
        float m = -INFINITY;
        for (int e = 0; e < N_EXPERTS; ++e) {
            const float v = lt[t][e];
            m = fmaxf(m, v);
            if (v > tv[TOP_K - 1]) {
#pragma unroll
                for (int j = TOP_K - 1; j >= 1; --j) {
                    const bool shift = (v > tv[j - 1]);
                    const bool here  = (v > tv[j]);
                    const float ntv = shift ? tv[j - 1] : (here ? v : tv[j]);
                    const int   nti = shift ? ti[j - 1] : (here ? e : ti[j]);
                    tv[j] = ntv; ti[j] = nti;
                }
                if (v > tv[0]) { tv[0] = v; ti[0] = e; }
            }
        }
        float s = 0.f;
        for (int e = 0; e < N_EXPERTS; ++e) s += expf(lt[t][e] - m);
        const float rs = 1.f / s;
        smax[t] = m; srs[t] = rs;
        float ex[TOP_K]; float wsum = 0.f;
#pragma unroll
        for (int i = 0; i < TOP_K; ++i) { ex[i] = expf(tv[i] - tv[0]); wsum += ex[i]; }
        const float rw = 1.f / wsum;
        const int tok = m0 + t;
#pragma unroll
        for (int i = 0; i < TOP_K; ++i) {
            out_idx[(size_t)tok * TOP_K + i] = (float)ti[i];
            out_w  [(size_t)tok * TOP_K + i] = ex[i] * rw;
        }
    }
    __syncthreads();
#pragma unroll
    for (int rep = 0; rep < 2; ++rep) {
        const int f = rep * (NTHREADS * 4) + tid * 4;
        const int t = f >> 6;
        const int e = f & 63;
        const float l0 = lt[t][e], l1 = lt[t][e+1], l2 = lt[t][e+2], l3 = lt[t][e+3];
        const float mm = smax[t], rr = srs[t];
        float4 pv = make_float4(expf(l0-mm)*rr, expf(l1-mm)*rr, expf(l2-mm)*rr, expf(l3-mm)*rr);
        float4 lv = make_float4(l0, l1, l2, l3);
        const size_t gbase = (size_t)m0 * N_EXPERTS + f;
        *(float4*)(out_p + gbase) = pv;
        *(float4*)(out_l + gbase) = lv;
    }
}

extern "C" void kernel_launch(void* const* d_in, const int* in_sizes, int n_in,
                              void* d_out, int out_size, void* d_ws, size_t ws_size,
                              hipStream_t stream) {
    const float* x  = (const float*)d_in[0];
    const float* gw = (const float*)d_in[1];
    float* out = (float*)d_out;
    if (ws_size >= (size_t)WS_NEED) {
        unsigned* wp = (unsigned*)d_ws;
        pack_w_kernel<<<dim3(WS_NEED / 4 / 256), dim3(256), 0, stream>>>(gw, wp);
        router_mfma<<<dim3(N_TOKENS / TOK_TILE), dim3(NTHREADS), 0, stream>>>(x, wp, out);
    } else {
        router_fallback<<<dim3(N_TOKENS / TOK_TILE), dim3(NTHREADS), 0, stream>>>(x, gw, out);
    }
}

// Round 4
// 74.204 us; speedup vs baseline: 3.9366x; 1.0078x over previous
//
#include <hip/hip_runtime.h>
#include <math.h>

#define D_MODEL   2048
#define N_EXPERTS 64
#define TOP_K     8
#define N_TOKENS  16384
#define TOK_TILE  64
#define NTHREADS  512
// ws layout: [kstep 0..63][nfrag 0..3][ver 0..2][lane 0..63][4 dwords]
#define WS_NEED   (64*4*3*64*16)   // 786432 bytes

typedef __attribute__((ext_vector_type(8))) short bf16x8;
typedef __attribute__((ext_vector_type(4))) float f32x4;
typedef __attribute__((ext_vector_type(4))) int   i32x4;

union FragU { i32x4 i; bf16x8 h; };

// exact 3-way truncation split: x == h+m+l + eps, |eps| <= 2^-24 |x|
__device__ __forceinline__ void split3(float x, unsigned &h, unsigned &m, unsigned &l) {
    unsigned ux = __float_as_uint(x);
    h = ux & 0xffff0000u;
    float mf = x - __uint_as_float(h);       // exact (Sterbenz)
    unsigned um = __float_as_uint(mf) & 0xffff0000u;
    float lf = mf - __uint_as_float(um);     // exact
    m = um;
    l = __float_as_uint(lf) & 0xffff0000u;
}

// ---- unchanged from R2 (HW-proven numerics + layout) ----
__global__ __launch_bounds__(256) void pack_w_kernel(const float* __restrict__ gw,
                                                     unsigned* __restrict__ wp) {
    const int g    = blockIdx.x * 256 + threadIdx.x;   // 0..196607
    const int d    = g & 3;
    const int lane = (g >> 2) & 63;
    const int rest = g >> 8;                           // 0..767
    const int v    = rest % 3;
    const int t    = rest / 3;                         // ks*4 + fr
    const int fr   = t & 3;
    const int ks   = t >> 2;
    const int e    = fr * 16 + (lane & 15);            // B col = lane&15
    const int k    = ks * 32 + (lane >> 4) * 8 + 2 * d;
    const float w0 = gw[(size_t)e * D_MODEL + k];
    const float w1 = gw[(size_t)e * D_MODEL + k + 1];
    unsigned h0, m0, l0, h1, m1, l1;
    split3(w0, h0, m0, l0);
    split3(w1, h1, m1, l1);
    const unsigned c0 = (v == 0) ? h0 : ((v == 1) ? m0 : l0);
    const unsigned c1 = (v == 0) ? h1 : ((v == 1) ? m1 : l1);
    wp[g] = (c0 >> 16) | c1;                           // low short = elem0
}

__device__ __forceinline__ void splitpack(const float4 a, const float4 b,
                                          FragU &ph, FragU &pm, FragU &pl) {
    const float f[8] = {a.x, a.y, a.z, a.w, b.x, b.y, b.z, b.w};
#pragma unroll
    for (int d = 0; d < 4; ++d) {
        unsigned h0, m0, l0, h1, m1, l1;
        split3(f[2 * d],     h0, m0, l0);
        split3(f[2 * d + 1], h1, m1, l1);
        ph.i[d] = (int)((h0 >> 16) | h1);
        pm.i[d] = (int)((m0 >> 16) | m1);
        pl.i[d] = (int)((l0 >> 16) | l1);
    }
}

#define MFMA(A_, B_, C_) C_ = __builtin_amdgcn_mfma_f32_16x16x32_bf16((A_).h, (B_).h, C_, 0, 0, 0)

__global__ __launch_bounds__(NTHREADS) void router_mfma(
    const float* __restrict__ x, const unsigned* __restrict__ wp,
    float* __restrict__ out)
{
    // x tile staged in LDS, double-buffered. 64 rows x 64 floats (256B rows).
    // XOR swizzle on 16B slots: slot' = slot ^ ((row&7)<<1) — breaks the
    // stride-256B 16-way bank conflict while keeping float4 alignment.
    __shared__ __align__(16) float xs[2][TOK_TILE][64];
    __shared__ float lt[TOK_TILE][N_EXPERTS + 1];
    __shared__ float smax[TOK_TILE], srs[TOK_TILE];

    const int tid  = threadIdx.x;
    const int lane = tid & 63;
    const int wv   = tid >> 6;          // 0..7
    const int mrow = wv & 3;            // token quarter (16 rows)
    const int ncol = wv >> 2;           // expert half (32 cols)
    const int m0   = blockIdx.x * TOK_TILE;

    const int lrow = lane & 15;         // A row / B col / C col
    const int lk   = lane >> 4;         // k-group 0..3

    // ---- staging coords: thread -> (row, two 16B slots) ----
    const int sr   = tid >> 3;          // 0..63
    const int s0   = tid & 7;           // slot 0..7 (second slot = +8)
    const int wswz = (sr & 7) << 1;
    float* dstA = &xs[0][sr][4 * (s0 ^ wswz)];
    float* dstB = &xs[0][sr][4 * ((s0 ^ wswz) ^ 8)];   // (s0+8)^w == (s0^w)^8
    const float* xsrc = x + (size_t)(m0 + sr) * D_MODEL + 4 * s0;

    // prologue: chunk 0 -> buf 0
    float4 xa = *(const float4*)(xsrc);
    float4 xb = *(const float4*)(xsrc + 32);
    *(float4*)dstA = xa;
    *(float4*)dstB = xb;

    f32x4 acc0a = {0.f, 0.f, 0.f, 0.f};
    f32x4 acc0b = acc0a, acc1a = acc0a, acc1b = acc0a;

    const unsigned* wb = wp + (size_t)(ncol * 6) * 256 + lane * 4;
    const int arow = mrow * 16 + lrow;
    const int amsk = (lrow & 7) << 1;   // (arow&7)<<1 since mrow*16 ≡ 0 mod 8
    const int LBUF = TOK_TILE * 64;     // dwords per LDS buffer
    __syncthreads();

    for (int c = 0; c < 32; ++c) {
        // issue next chunk's global loads early (latency hides under compute)
        if (c + 1 < 32) {
            xa = *(const float4*)(xsrc + (c + 1) * 64);
            xb = *(const float4*)(xsrc + (c + 1) * 64 + 32);
        }
        const float* xbuf = &xs[c & 1][0][0];
#pragma unroll
        for (int j = 0; j < 2; ++j) {
            const int ks = 2 * c + j;
            const unsigned* bt = wb + (size_t)ks * 3072;
            i32x4 B0h = *(const i32x4*)(bt +    0);
            i32x4 B0m = *(const i32x4*)(bt +  256);
            i32x4 B0l = *(const i32x4*)(bt +  512);
            i32x4 B1h = *(const i32x4*)(bt +  768);
            i32x4 B1m = *(const i32x4*)(bt + 1024);
            i32x4 B1l = *(const i32x4*)(bt + 1280);

            const int slot = (j * 8 + 2 * lk) ^ amsk;
            const float* ap = xbuf + arow * 64 + 4 * slot;
            const float4 Aa = *(const float4*)(ap);
            const float4 Ab = *(const float4*)(ap + 4);

            FragU ah, am, al;
            splitpack(Aa, Ab, ah, am, al);
            FragU b0h, b0m, b0l, b1h, b1m, b1l;
            b0h.i = B0h; b0m.i = B0m; b0l.i = B0l;
            b1h.i = B1h; b1m.i = B1m; b1l.i = B1l;

            // 6 split terms per expert-frag, 4 independent chains (depth 3)
            MFMA(ah, b0h, acc0a); MFMA(am, b0h, acc0a); MFMA(al, b0h, acc0a);
            MFMA(ah, b0m, acc0b); MFMA(am, b0m, acc0b); MFMA(ah, b0l, acc0b);
            MFMA(ah, b1h, acc1a); MFMA(am, b1h, acc1a); MFMA(al, b1h, acc1a);
            MFMA(ah, b1m, acc1b); MFMA(am, b1m, acc1b); MFMA(ah, b1l, acc1b);
        }
        // write next chunk into the other buffer, then one barrier per chunk
        if (c + 1 < 32) {
            const int off = ((c + 1) & 1) * LBUF;
            *(float4*)(dstA + off) = xa;
            *(float4*)(dstB + off) = xb;
        }
        __syncthreads();
    }

    // ---- C scatter. Layout (m89/R2-verified): col=lane&15, row=(lane>>4)*4+reg
#pragma unroll
    for (int r = 0; r < 4; ++r) {
        lt[mrow * 16 + lk * 4 + r][ncol * 32 +  0 + lrow] = acc0a[r] + acc0b[r];
        lt[mrow * 16 + lk * 4 + r][ncol * 32 + 16 + lrow] = acc1a[r] + acc1b[r];
    }
    __syncthreads();

    // ---- epilogue: identical to the R0/R2-proven path ----
    float* out_idx = out;
    float* out_w   = out + (size_t)N_TOKENS * TOP_K;
    float* out_p   = out + (size_t)2 * N_TOKENS * TOP_K;
    float* out_l   = out_p + (size_t)N_TOKENS * N_EXPERTS;

    if (tid < TOK_TILE) {
        const int t = tid;
        float tv[TOP_K];
        int   ti[TOP_K];
#pragma unroll
        for (int i = 0; i < TOP_K; ++i) { tv[i] = -INFINITY; ti[i] = 0; }
        float m = -INFINITY;

        for (int e = 0; e < N_EXPERTS; ++e) {
            const float v = lt[t][e];
            m = fmaxf(m, v);
            if (v > tv[TOP_K - 1]) {
#pragma unroll
                for (int j = TOP_K - 1; j >= 1; --j) {
                    const bool shift = (v > tv[j - 1]);
                    const bool here  = (v > tv[j]);
                    const float ntv = shift ? tv[j - 1] : (here ? v : tv[j]);
                    const int   nti = shift ? ti[j - 1] : (here ? e : ti[j]);
                    tv[j] = ntv; ti[j] = nti;
                }
                if (v > tv[0]) { tv[0] = v; ti[0] = e; }
            }
        }

        float s = 0.f;
        for (int e = 0; e < N_EXPERTS; ++e) s += expf(lt[t][e] - m);
        const float rs = 1.f / s;
        smax[t] = m;
        srs[t]  = rs;

        float ex[TOP_K];
        float wsum = 0.f;
#pragma unroll
        for (int i = 0; i < TOP_K; ++i) { ex[i] = expf(tv[i] - tv[0]); wsum += ex[i]; }
        const float rw = 1.f / wsum;

        const int tok = m0 + t;
#pragma unroll
        for (int i = 0; i < TOP_K; ++i) {
            out_idx[(size_t)tok * TOP_K + i] = (float)ti[i];
            out_w  [(size_t)tok * TOP_K + i] = ex[i] * rw;
        }
    }
    __syncthreads();

#pragma unroll
    for (int rep = 0; rep < 2; ++rep) {
        const int f = rep * (NTHREADS * 4) + tid * 4;
        const int t = f >> 6;
        const int e = f & 63;
        const float l0 = lt[t][e + 0];
        const float l1 = lt[t][e + 1];
        const float l2 = lt[t][e + 2];
        const float l3 = lt[t][e + 3];
        const float mm = smax[t];
        const float rr = srs[t];
        float4 pv = make_float4(expf(l0 - mm) * rr, expf(l1 - mm) * rr,
                                expf(l2 - mm) * rr, expf(l3 - mm) * rr);
        float4 lv = make_float4(l0, l1, l2, l3);
        const size_t gbase = (size_t)m0 * N_EXPERTS + f;
        *(float4*)(out_p + gbase) = pv;
        *(float4*)(out_l + gbase) = lv;
    }
}

// ---------------- fallback (R0-proven fp32 path) if ws too small ----------------
__global__ __launch_bounds__(NTHREADS) void router_fallback(
    const float* __restrict__ x, const float* __restrict__ gw,
    float* __restrict__ out)
{
    __shared__ float xs[TOK_TILE][33];
    __shared__ float wsh[N_EXPERTS][36];
    __shared__ float lt[TOK_TILE][N_EXPERTS + 1];
    __shared__ float smax[TOK_TILE], srs[TOK_TILE];

    const int tid  = threadIdx.x;
    const int lane = tid & 63;
    const int wv   = tid >> 6;
    const int m0   = blockIdx.x * TOK_TILE;
    const int srow = tid >> 3;
    const int skq  = (tid & 7) * 4;

    const float* xsrc = x  + (size_t)(m0 + srow) * D_MODEL + skq;
    const float* wsrc = gw + (size_t)srow        * D_MODEL + skq;
    float4 xr = *(const float4*)(xsrc);
    float4 wr = *(const float4*)(wsrc);

    float acc[8];
#pragma unroll
    for (int i = 0; i < 8; ++i) acc[i] = 0.f;
    const int e0 = wv * 8;

    for (int c = 0; c < D_MODEL / 32; ++c) {
        xs[srow][skq] = xr.x; xs[srow][skq+1] = xr.y; xs[srow][skq+2] = xr.z; xs[srow][skq+3] = xr.w;
        *(float4*)&wsh[srow][skq] = wr;
        __syncthreads();
        if (c + 1 < D_MODEL / 32) {
            xr = *(const float4*)(xsrc + (c + 1) * 32);
            wr = *(const float4*)(wsrc + (c + 1) * 32);
        }
#pragma unroll 8
        for (int k4 = 0; k4 < 8; ++k4) {
            const float4 xv = *(const float4*)&xs[lane][k4 * 4];
#pragma unroll
            for (int e = 0; e < 8; ++e) {
                const float4 w4 = *(const float4*)&wsh[e0 + e][k4 * 4];
                acc[e] = fmaf(xv.x, w4.x, fmaf(xv.y, w4.y, fmaf(xv.z, w4.z, fmaf(xv.w, w4.w, acc[e]))));
            }
        }
        __syncthreads();
    }
#pragma unroll
    for (int e = 0; e < 8; ++e) lt[lane][e0 + e] = acc[e];
    __syncthreads();

    float* out_idx = out;
    float* out_w   = out + (size_t)N_TOKENS * TOP_K;
    float* out_p   = out + (size_t)2 * N_TOKENS * TOP_K;
    float* out_l   = out_p + (size_t)N_TOKENS * N_EXPERTS;

    if (tid < TOK_TILE) {
        const int t = tid;
        float tv[TOP_K]; int ti[TOP_K];
#pragma unroll
        for (int i = 0; i < TOP_K; ++i) { tv[i] = -INFINITY; ti[i] = 0; }
        float m = -INFINITY;
        for (int e = 0; e < N_EXPERTS; ++e) {
            const float v = lt[t][e];
            m = fmaxf(m, v);
            if (v > tv[TOP_K - 1]) {
#pragma unroll
                for (int j = TOP_K - 1; j >= 1; --j) {
                    const bool shift = (v > tv[j - 1]);
                    const bool here  = (v > tv[j]);
                    const float ntv = shift ? tv[j - 1] : (here ? v : tv[j]);
                    const int   nti = shift ? ti[j - 1] : (here ? e : ti[j]);
                    tv[j] = ntv; ti[j] = nti;
                }
                if (v > tv[0]) { tv[0] = v; ti[0] = e; }
            }
        }
        float s = 0.f;
        for (int e = 0; e < N_EXPERTS; ++e) s += expf(lt[t][e] - m);
        const float rs = 1.f / s;
        smax[t] = m; srs[t] = rs;
        float ex[TOP_K]; float wsum = 0.f;
#pragma unroll
        for (int i = 0; i < TOP_K; ++i) { ex[i] = expf(tv[i] - tv[0]); wsum += ex[i]; }
        const float rw = 1.f / wsum;
        const int tok = m0 + t;
#pragma unroll
        for (int i = 0; i < TOP_K; ++i) {
            out_idx[(size_t)tok * TOP_K + i] = (float)ti[i];
            out_w  [(size_t)tok * TOP_K + i] = ex[i] * rw;
        }
    }
    __syncthreads();
#pragma unroll
    for (int rep = 0; rep < 2; ++rep) {
        const int f = rep * (NTHREADS * 4) + tid * 4;
        const int t = f >> 6;
        const int e = f & 63;
        const float l0 = lt[t][e], l1 = lt[t][e+1], l2 = lt[t][e+2], l3 = lt[t][e+3];
        const float mm = smax[t], rr = srs[t];
        float4 pv = make_float4(expf(l0-mm)*rr, expf(l1-mm)*rr, expf(l2-mm)*rr, expf(l3-mm)*rr);
        float4 lv = make_float4(l0, l1, l2, l3);
        const size_t gbase = (size_t)m0 * N_EXPERTS + f;
        *(float4*)(out_p + gbase) = pv;
        *(float4*)(out_l + gbase) = lv;
    }
}

extern "C" void kernel_launch(void* const* d_in, const int* in_sizes, int n_in,
                              void* d_out, int out_size, void* d_ws, size_t ws_size,
                              hipStream_t stream) {
    const float* x  = (const float*)d_in[0];
    const float* gw = (const float*)d_in[1];
    float* out = (float*)d_out;
    if (ws_size >= (size_t)WS_NEED) {
        unsigned* wp = (unsigned*)d_ws;
        pack_w_kernel<<<dim3(WS_NEED / 4 / 256), dim3(256), 0, stream>>>(gw, wp);
        router_mfma<<<dim3(N_TOKENS / TOK_TILE), dim3(NTHREADS), 0, stream>>>(x, wp, out);
    } else {
        router_fallback<<<dim3(N_TOKENS / TOK_TILE), dim3(NTHREADS), 0, stream>>>(x, gw, out);
    }
}